// Round 10
// baseline (251.895 us; speedup 1.0000x reference)
//
#include <hip/hip_runtime.h>
#include <hip/hip_bf16.h>

// MinGRU forward: z=sigmoid(xWz^T), h~=xWh^T, a=1-z+1e-8, b=z*h~, scan h=a*h+b.
// B=4 T=4096 D=1024.
// R13: (1) K-loop restructured to the T3-minimum 2-phase pipeline (guide §5.5
// T3 recipe): BK=32 double-buffered LDS (2x24KB, same 48KB footprint ->
// occupancy unchanged); per iteration issue 6 stage loads for tile k+1 BEFORE
// computing tile k, one barrier per tile. R12's loop fully exposed the stage
// latency (sync -> stage -> sync+drain -> compute: nothing in flight during
// the drain). (2) vbid mapping bx-fastest (bx=vbid&127, by=vbid>>7):
// consecutive tickets share the W slice (L2-hot) and chain predecessors are
// immediate ticket neighbors (short lookback); X re-reads across by-groups
// are L3-absorbed. Spine protocol unchanged from R12 (RMW-only, proven
// correct+cheap). Scan algebra unchanged.

typedef __bf16 bf16x8 __attribute__((ext_vector_type(8)));
typedef float  f32x4  __attribute__((ext_vector_type(4)));

#define BSZ 4
#define TSZ 4096
#define DSZ 1024
#define MSZ (BSZ*TSZ)      // 16384 rows
#define CH  16             // scan chunk length
#define NC  (TSZ/CH)       // 256 chunks per sequence
#define CPB 32             // chain length in blocks (4096 rows / 128)
#define NBLK 1024          // total gemm blocks (128 x-tiles * 8 y-tiles)

__device__ __forceinline__ void gload_lds16(const __bf16* g, __bf16* l) {
  __builtin_amdgcn_global_load_lds(
      (const __attribute__((address_space(1))) void*)g,
      (__attribute__((address_space(3))) void*)l, 16, 0, 0);
}

// ---- spine access: RMW-only (executes at coherence point, no cache ops) ----
__device__ __forceinline__ void  spineWr(float* p, float v) {
  (void)__hip_atomic_exchange(p, v, __ATOMIC_RELAXED, __HIP_MEMORY_SCOPE_AGENT);
}
__device__ __forceinline__ float spineRd(float* p) {
  return __hip_atomic_fetch_add(p, 0.0f, __ATOMIC_RELAXED, __HIP_MEMORY_SCOPE_AGENT);
}
__device__ __forceinline__ void  flagWr(int* p, int v) {
  (void)__hip_atomic_exchange(p, v, __ATOMIC_RELAXED, __HIP_MEMORY_SCOPE_AGENT);
}
__device__ __forceinline__ int   flagRd(int* p) {
  return __hip_atomic_fetch_add(p, 0, __ATOMIC_RELAXED, __HIP_MEMORY_SCOPE_AGENT);
}

// ---------------- conversion: fp32 row-major -> bf16 fragment-tiled ----------------
// tiled layout: [rowblk][kblk:32][i:8][l:64][j:8] where
//   row = rowblk*128 + i*16 + (l&15), k = kblk*32 + (l>>4)*8 + j
// Block 0 zeroes spine flags + ticket; kernel-boundary release makes it
// visible to gemm_scan's coherence-point RMWs.
__global__ void convert_tile_kernel(const float* __restrict__ X,
                                    const float* __restrict__ Wz,
                                    const float* __restrict__ Wh,
                                    __bf16* __restrict__ Xc,
                                    __bf16* __restrict__ Wzc,
                                    __bf16* __restrict__ Whc,
                                    int* __restrict__ ctrl)
{
  const int bx = blockIdx.x;
  if (bx == 0) {
    #pragma unroll
    for (int k = 0; k < 4; ++k) ctrl[k*256 + threadIdx.x] = 0;
    if (threadIdx.x == 0) ctrl[NBLK] = 0;      // ticket
  }
  const float* src; __bf16* dst; int gid;
  if (bx < 8192)      { src = X;  dst = Xc;  gid =  bx        *256 + threadIdx.x; }
  else if (bx < 8704) { src = Wz; dst = Wzc; gid = (bx - 8192)*256 + threadIdx.x; }
  else                { src = Wh; dst = Whc; gid = (bx - 8704)*256 + threadIdx.x; }
  const int l    = gid & 63;
  const int i    = (gid >> 6) & 7;
  const int kblk = (gid >> 9) & 31;
  const int rblk = gid >> 14;
  const int row  = rblk*128 + i*16 + (l & 15);
  const int col  = kblk*32 + (l >> 4)*8;
  const float* g = src + (size_t)row*DSZ + col;
  float4 v0 = *(const float4*)g;
  float4 v1 = *(const float4*)(g + 4);
  bf16x8 p;
  p[0]=(__bf16)v0.x; p[1]=(__bf16)v0.y; p[2]=(__bf16)v0.z; p[3]=(__bf16)v0.w;
  p[4]=(__bf16)v1.x; p[5]=(__bf16)v1.y; p[6]=(__bf16)v1.z; p[7]=(__bf16)v1.w;
  *(bf16x8*)(dst + (size_t)gid*8) = p;
}

// ---------------- fused GEMM + gate + full scan + final output ----------------
// block tile 128(M) x 128(N), BK=32 double-buffered; 256 threads = 4 waves 2x2.
__global__ __launch_bounds__(256, 2) void gemm_scan_kernel(
    const __bf16* __restrict__ Xc,  const __bf16* __restrict__ Wzc,
    const __bf16* __restrict__ Whc,
    const float* __restrict__ bz, const float* __restrict__ bh,
    float* __restrict__ out,
    float* aggA, float* aggB, float* incA, float* incB, int* ctrl)
{
  // [buf:2][4096 elems] per matrix -> 8KB x2 x3 = 48KB total
  __shared__ __align__(16) __bf16 As [8192];
  __shared__ __align__(16) __bf16 Bzs[8192];
  __shared__ __align__(16) __bf16 Bhs[8192];
  __shared__ int vbid_s;

  const int tid  = threadIdx.x;
  // ---- ticket: dispatch-order-independent chain position ----
  if (tid == 0)
    vbid_s = __hip_atomic_fetch_add(&ctrl[NBLK], 1, __ATOMIC_RELAXED,
                                    __HIP_MEMORY_SCOPE_AGENT) & (NBLK - 1);
  __syncthreads();
  const int vbid = vbid_s;
  const int bx = vbid & 127;           // M tile (chain position), FASTEST
  const int by = vbid >> 7;            // N tile -> W slice stays L2-hot per phase

  const int lane = tid & 63;
  const int wv   = tid >> 6;
  const int wM   = (wv >> 1) * 64;
  const int wN   = (wv & 1) * 64;
  const int wMg  = wM >> 4;
  const int wNg  = wN >> 4;
  const int lr   = lane & 15;
  const int q    = lane >> 4;
  const int wr   = wv >> 1;
  const int wbase = wv * 64;           // wave-uniform

  const __bf16* Xb = Xc  + (size_t)bx * 32 * 4096;
  const __bf16* Zb = Wzc + (size_t)by * 32 * 4096;
  const __bf16* Hb = Whc + (size_t)by * 32 * 4096;

  f32x4 accz[4][4] = {};
  f32x4 acch[4][4] = {};

  // staging offsets: 256 thr x 16B x 2 rounds covers one 4096-elem kblk tile
  const int eo0 = (wbase + lane) * 8;         // per-lane global elem offset, round 0
  const int eo1 = (256 + wbase + lane) * 8;   // round 1
  const int lo0 = wbase * 8;                  // wave-uniform LDS elem offset
  const int lo1 = (256 + wbase) * 8;

  // ---- prologue: stage kblk 0 into buf0 ----
  {
    gload_lds16(Xb + eo0, As  + lo0);  gload_lds16(Xb + eo1, As  + lo1);
    gload_lds16(Zb + eo0, Bzs + lo0);  gload_lds16(Zb + eo1, Bzs + lo1);
    gload_lds16(Hb + eo0, Bhs + lo0);  gload_lds16(Hb + eo1, Bhs + lo1);
  }
  __syncthreads();   // implicit vmcnt(0): buf0 ready

  // ---- T3-minimum pipeline: stage(k+1) BEFORE compute(k); 1 barrier/tile ----
  for (int kb = 0; kb < 32; ++kb) {
    const int cur = (kb & 1) * 4096;
    const int nxt = cur ^ 4096;
    if (kb < 31) {
      const size_t g = (size_t)(kb + 1) * 4096;
      gload_lds16(Xb + g + eo0, As  + nxt + lo0);
      gload_lds16(Xb + g + eo1, As  + nxt + lo1);
      gload_lds16(Zb + g + eo0, Bzs + nxt + lo0);
      gload_lds16(Zb + g + eo1, Bzs + nxt + lo1);
      gload_lds16(Hb + g + eo0, Bhs + nxt + lo0);
      gload_lds16(Hb + g + eo1, Bhs + nxt + lo1);
    }
    bf16x8 af[4];
    #pragma unroll
    for (int i = 0; i < 4; ++i)
      af[i] = *(const bf16x8*)(As + cur + (wMg + i)*512 + lane*8);
    #pragma unroll
    for (int j = 0; j < 4; ++j) {
      bf16x8 bz8 = *(const bf16x8*)(Bzs + cur + (wNg + j)*512 + lane*8);
      bf16x8 bh8 = *(const bf16x8*)(Bhs + cur + (wNg + j)*512 + lane*8);
      #pragma unroll
      for (int i = 0; i < 4; ++i) {
        accz[j][i] = __builtin_amdgcn_mfma_f32_16x16x32_bf16(af[i], bz8, accz[j][i], 0, 0, 0);
        acch[j][i] = __builtin_amdgcn_mfma_f32_16x16x32_bf16(af[i], bh8, acch[j][i], 0, 0, 0);
      }
    }
    __syncthreads();   // implicit vmcnt(0): next buf staged; cur reads done
  }

  // ===================== fused scan epilogue =====================
  // C/D layout col=lane&15, row=(lane>>4)*4+reg (verified m89/m91).
  // CH=16 -> chunk_local = wr*4 + i (8 chunks per block of 128 rows).
  const int M0 = bx * 128, N0 = by * 128;
  const int cb = bx & ~(CPB-1);                 // chain base (sequence start)
  const int fidx = vbid;                        // spine slot == vbid

  __syncthreads();                              // K-loop LDS reads done; reuse As
  float* ldsA = (float*)As;                     // [8][128] chunk agg A (4KB)
  float* ldsB = ldsA + 1024;                    // [8][128] chunk agg B (4KB)
  float* hsL  = ldsB + 1024;                    // [8][128] chunk Hstart (4KB)

  // ---- pass A: per-chunk aggregates + exclusive q-prefixes ----
  float EA[4][4], EB[4][4];
  #pragma unroll
  for (int j = 0; j < 4; ++j) {
    const int e = N0 + wN + j*16 + lr;
    const float bzv = bz[e];
    const float bhv = bh[e];
    #pragma unroll
    for (int i = 0; i < 4; ++i) {
      float A = 1.0f, Bv = 0.0f;
      #pragma unroll
      for (int r = 0; r < 4; ++r) {
        const float pz = accz[j][i][r] + bzv;
        const float ph = acch[j][i][r] + bhv;
        const float ex = __expf(-pz);
        const float z  = 1.0f / (1.0f + ex);
        const float af = fmaf(ex, z, 1e-8f);    // (1-z) + 1e-8, f32 throughout
        const float bf = z * ph;
        Bv = fmaf(af, Bv, bf);
        A *= af;
      }
      // inclusive scan across the 4 q-lane groups (stride 16)
      float sA = A, sB = Bv;
      #pragma unroll
      for (int s = 16; s < 64; s <<= 1) {
        const float Ap = __shfl_up(sA, s, 64);
        const float Bp = __shfl_up(sB, s, 64);
        if (lane >= s) { sB = fmaf(sA, Bp, sB); sA *= Ap; }
      }
      float eA = __shfl_up(sA, 16, 64);
      float eB = __shfl_up(sB, 16, 64);
      if (q == 0) { eA = 1.0f; eB = 0.0f; }
      EA[j][i] = eA; EB[j][i] = eB;
      // chunk aggregate lives at q==3; stash to LDS (one writer per d)
      const float cA = __shfl(sA, 48 + lr, 64);
      const float cB = __shfl(sB, 48 + lr, 64);
      if (q == 0) {
        ldsA[(wr*4 + i)*128 + (e - N0)] = cA;
        ldsB[(wr*4 + i)*128 + (e - N0)] = cB;
      }
    }
  }
  __syncthreads();

  // ---- spine: block aggregate publish (waves wr==1, q==0 lanes own 128 d) ----
  float bA[4], bB[4];
  if (wr == 1 && q == 0) {
    #pragma unroll
    for (int j = 0; j < 4; ++j) {
      const int dl = wN + j*16 + lr;
      float A = 1.0f, Bv = 0.0f;
      #pragma unroll
      for (int c = 0; c < 8; ++c) {             // compose 8 chunks in time order
        const float cA = ldsA[c*128 + dl];
        const float cB = ldsB[c*128 + dl];
        Bv = fmaf(cA, Bv, cB);
        A *= cA;
      }
      bA[j] = A; bB[j] = Bv;
      const size_t sidx = (size_t)fidx*128 + dl;
      spineWr(&aggA[sidx], A);
      spineWr(&aggB[sidx], Bv);
    }
  }
  __syncthreads();   // implicit vmcnt(0): payload RMWs acked at coherence point
  if (tid == 0) flagWr(&ctrl[fidx], 1);

  // ---- lookback: exclusive block prefix per d; then chunk Hstarts ----
  // Spins only on lower-vbid blocks (earlier tickets => already executing =>
  // publish flag=1 with no upstream spin) -> deadlock-free under any dispatch.
  if (wr == 1 && q == 0) {
    float Aex[4] = {1.f,1.f,1.f,1.f}, Bex[4] = {0.f,0.f,0.f,0.f};
    for (int kx = bx - 1; kx >= cb; --kx) {
      const int k = by*128 + kx;                // spine slot of predecessor
      int f;
      do {
        f = flagRd(&ctrl[k]);
        f = __builtin_amdgcn_readfirstlane(f);
        if (f == 0) __builtin_amdgcn_s_sleep(16);
      } while (f == 0);
      float* pA = (f == 2) ? incA : aggA;
      float* pB = (f == 2) ? incB : aggB;
      #pragma unroll
      for (int j = 0; j < 4; ++j) {
        const int dl = wN + j*16 + lr;
        const size_t sidx = (size_t)k*128 + dl;
        const float kA = spineRd(&pA[sidx]);
        const float kB = spineRd(&pB[sidx]);
        // cur (Aex,Bex) covers [kx+1, bx-1]; prepend earlier segment kx:
        Bex[j] = fmaf(Aex[j], kB, Bex[j]);
        Aex[j] *= kA;
      }
      if (f == 2) break;                        // composed a full inclusive prefix
    }
    #pragma unroll
    for (int j = 0; j < 4; ++j) {
      const int dl = wN + j*16 + lr;
      const size_t sidx = (size_t)fidx*128 + dl;
      // inclusive = own_agg o exclusive
      spineWr(&incA[sidx], Aex[j]*bA[j]);
      spineWr(&incB[sidx], fmaf(bA[j], Bex[j], bB[j]));
      // chunk Hstarts: h at block start = Bex (upstream applied to h0=0)
      float h = Bex[j];
      #pragma unroll
      for (int c = 0; c < 8; ++c) {
        hsL[c*128 + dl] = h;
        h = fmaf(ldsA[c*128 + dl], h, ldsB[c*128 + dl]);
      }
    }
  }
  __syncthreads();   // implicit vmcnt(0): inc RMWs acked; hsL visible
  if (tid == 0) flagWr(&ctrl[fidx], 2);

  // ---- pass B: recompute gate, apply prefix, write FINAL out ----
  #pragma unroll
  for (int j = 0; j < 4; ++j) {
    const int e = N0 + wN + j*16 + lr;
    const float bzv = bz[e];
    const float bhv = bh[e];
    #pragma unroll
    for (int i = 0; i < 4; ++i) {
      const int mbase = M0 + wM + i*16 + q*4;
      const float hs = hsL[(wr*4 + i)*128 + (e - N0)];
      float A = 1.0f, Bv = 0.0f;
      #pragma unroll
      for (int r = 0; r < 4; ++r) {
        const float pz = accz[j][i][r] + bzv;
        const float ph = acch[j][i][r] + bhv;
        const float ex = __expf(-pz);
        const float z  = 1.0f / (1.0f + ex);
        const float af = fmaf(ex, z, 1e-8f);
        const float bf = z * ph;
        Bv = fmaf(af, Bv, bf);
        A *= af;
        // within-chunk prefix at this row: Apre = A*EA, Bpre = A*EB + Bv
        const float Apre = A * EA[j][i];
        const float Bpre = fmaf(A, EB[j][i], Bv);
        out[(size_t)(mbase + r)*DSZ + e] = fmaf(Apre, hs, Bpre);
      }
    }
  }
}

extern "C" void kernel_launch(void* const* d_in, const int* in_sizes, int n_in,
                              void* d_out, int out_size, void* d_ws, size_t ws_size,
                              hipStream_t stream)
{
  const float* x  = (const float*)d_in[0];
  const float* Wz = (const float*)d_in[1];
  const float* bz = (const float*)d_in[2];
  const float* Wh = (const float*)d_in[3];
  const float* bh = (const float*)d_in[4];
  float* out = (float*)d_out;

  // ws: Xc (32MB) | Wzc (2MB) | Whc (2MB) | aggA/aggB/incA/incB (512KB ea) | ctrl (4KB+4)
  __bf16* Xc   = (__bf16*)d_ws;
  __bf16* Wzc  = Xc  + (size_t)MSZ * DSZ;
  __bf16* Whc  = Wzc + (size_t)DSZ * DSZ;
  float*  aggA = (float*)(Whc + (size_t)DSZ * DSZ);
  float*  aggB = aggA + (size_t)NBLK*128;
  float*  incA = aggB + (size_t)NBLK*128;
  float*  incB = incA + (size_t)NBLK*128;
  int*    ctrl = (int*)(incB + (size_t)NBLK*128);

  convert_tile_kernel<<<9216, 256, 0, stream>>>(x, Wz, Wh, Xc, Wzc, Whc, ctrl);
  gemm_scan_kernel<<<dim3(128, 8), 256, 0, stream>>>(
      Xc, Wzc, Whc, bz, bh, out, aggA, aggB, incA, incB, ctrl);
}